// Round 7
// baseline (550.953 us; speedup 1.0000x reference)
//
#include <hip/hip_runtime.h>
#include <hip/hip_bf16.h>

// DenoisingPotential: x_{t+1} = x_t + alpha * grad_phi(x_t), 10 iters.
// grad = (pacc - sum_k w_k y_k)/l,  y_k = P_k x,  w_k = exp(e_k + Pmu_k.x - 0.5 x.y_k)
//
// R10: R9 (s-outer MFMA emission, +4%) still exposes the per-k chain: the
// softmax VALU chain for k directly follows -- and depends on -- the MFMAs
// for k, so in-order issue stalls the wave ~MFMA-latency every k-step, and
// at 2 waves/SIMD nothing covers it. Fix: 2-deep software pipeline (T15
// pattern, static-named yA/yB + apA/apB per rule #20): per step, issue the
// MFMAs for k+1 BEFORE running the chain for k. Chain consumes a result
// issued a full step earlier; MFMA pipe stays fed during the chain; P-frag
// prefetch distance rises to 2 steps (~500cy >> L2 ~250cy). Iteration
// prologue issues k=0/1 loads before the pmx GEMM.

typedef __attribute__((ext_vector_type(4))) float f32x4;
typedef __attribute__((ext_vector_type(8))) short bf16x8;  // 8 bf16 = 4 VGPRs

#define KC 32
#define NITER 10
#define XROW 72        // bf16 elems per point-row in xs staging (pad vs 64)
#define WT_PITCH 40    // bf16 pitch of weight stash (pad vs 32)
#define PW_BYTES 7168  // per-wave: xsw(4608, aliased by pmxw 4096) + wtw(2560)
// LDS total: 4 * 7168 = 28672 B

static __device__ __forceinline__ unsigned pk_bf16(float a, float b) {
  __hip_bfloat16 ha = __float2bfloat16(a), hb = __float2bfloat16(b);
  unsigned short ua = *(unsigned short*)&ha, ub = *(unsigned short*)&hb;
  return (unsigned)ua | ((unsigned)ub << 16);
}

// butterfly sum with lane^16: permlane16_swap is pure VALU (sum of the two
// outputs = x[l] + x[l^16] in every lane)
static __device__ __forceinline__ float red16(float x) {
#if __has_builtin(__builtin_amdgcn_permlane16_swap)
  int xi = __float_as_int(x);
  auto pr = __builtin_amdgcn_permlane16_swap(xi, xi, false, false);
  return __int_as_float(pr[0]) + __int_as_float(pr[1]);
#else
  int v = __builtin_amdgcn_ds_swizzle(__float_as_int(x), 0x401F);
  return x + __int_as_float(v);
#endif
}
// butterfly sum with lane^32 (VALU permlane32_swap)
static __device__ __forceinline__ float red32(float x) {
  int xi = __float_as_int(x);
  auto pr = __builtin_amdgcn_permlane32_swap(xi, xi, false, false);
  return __int_as_float(pr[0]) + __int_as_float(pr[1]);
}

// ---------------- precompute 1: per-k P = A^T A, Pmu, e, swizzled P ----------
__global__ void precompute1(const float* __restrict__ A, const float* __restrict__ mu,
                            const float* __restrict__ c,
                            float* __restrict__ Pmu_g, float* __restrict__ e_g,
                            __hip_bfloat16* __restrict__ Psw) {
  __shared__ float As[64 * 64];
  __shared__ float Pk[64 * 64];
  const int k = blockIdx.x, tid = threadIdx.x;
  const float* Ak = A + k * 4096;
  for (int idx = tid; idx < 1024; idx += 256)
    *(f32x4*)&As[idx * 4] = *(const f32x4*)&Ak[idx * 4];
  __syncthreads();

  // thread -> row i = tid>>2, col strip lg*16..lg*16+15
  const int i = tid >> 2, lg = tid & 3;
  float acc[16] = {};
  for (int j = 0; j < 64; ++j) {
    float ai = As[j * 64 + i];  // broadcast within quad
    const f32x4* row = (const f32x4*)&As[j * 64 + lg * 16];  // broadcast across i
#pragma unroll
    for (int g = 0; g < 4; ++g) {
      f32x4 v = row[g];
#pragma unroll
      for (int r = 0; r < 4; ++r) acc[g * 4 + r] += ai * v[r];
    }
  }
#pragma unroll
  for (int g = 0; g < 4; ++g)
#pragma unroll
    for (int r = 0; r < 4; ++r) Pk[i * 64 + lg * 16 + g * 4 + r] = acc[g * 4 + r];
  __syncthreads();

  if (tid < 64) {
    // Pmu[i] = sum_l P[l][i]*mu[l]  (P symmetric; transposed read = stride-1)
    float s = 0.f;
    for (int l = 0; l < 64; ++l) s += Pk[l * 64 + tid] * mu[k * 64 + l];
    Pmu_g[k * 64 + tid] = s;
    float v = mu[k * 64 + tid] * s;
#pragma unroll
    for (int off = 1; off < 64; off <<= 1) v += __shfl_xor(v, off, 64);
    if (tid == 0) e_g[k] = c[k] - 0.5f * v;
  }

  // A-frag order for the main GEMM: flat idx = f*512 + lane*8 + j,
  // f=(mt,s): val = P[dim_in = s*32 + qq*8 + j][dim_out = mt*16 + l4]
  unsigned* Psw32 = (unsigned*)(Psw + k * 4096);
  for (int idx2 = tid; idx2 < 2048; idx2 += 256) {
    int idx = idx2 << 1;  // even j
    int f = idx >> 9, ln = (idx >> 3) & 63, j = idx & 7;
    int mt = f >> 1, s = f & 1, qq = ln >> 4, l4 = ln & 15;
    int col = mt * 16 + l4, rb = s * 32 + qq * 8 + j;
    Psw32[idx2] = pk_bf16(Pk[rb * 64 + col], Pk[(rb + 1) * 64 + col]);
  }
}

// ---------------- precompute 2: Pmu fragment swizzles -----------------------
__global__ void precompute2(const float* __restrict__ Pmu_g,
                            __hip_bfloat16* __restrict__ PmuA,
                            __hip_bfloat16* __restrict__ PmuB) {
  const int tid = threadIdx.x;
  // PmuA (pmx GEMM A-operand): A[m=cluster][kk=dim]; frag f=(mtc,s)
  for (int idx = tid; idx < 2048; idx += 256) {
    int f = idx >> 9, lane = (idx >> 3) & 63, j = idx & 7;
    int mtc = f >> 1, s = f & 1, qq = lane >> 4, l4 = lane & 15;
    PmuA[idx] = __float2bfloat16(Pmu_g[(mtc * 16 + l4) * 64 + s * 32 + qq * 8 + j]);
  }
  // PmuB (pacc GEMM A-operand): A[m=dim][kk=cluster]; frag f=mtd (K=32, 1 step)
  for (int idx = tid; idx < 2048; idx += 256) {
    int f = idx >> 9, lane = (idx >> 3) & 63, j = idx & 7;
    int qq = lane >> 4, l4 = lane & 15;
    PmuB[idx] = __float2bfloat16(Pmu_g[(qq * 8 + j) * 64 + f * 16 + l4]);
  }
}

// ---------------- main kernel ----------------------------------------------
// 256 thr (4 waves), 32 pts/wave, grid 512. NO __syncthreads anywhere; all
// LDS use is wave-private scratch. P via register buffers, 2-deep pipeline.
__launch_bounds__(256, 2)
__global__ void denoise_main(const float* __restrict__ x_in,
                             const float* __restrict__ e_g,
                             const float* __restrict__ alpha_g,
                             const __hip_bfloat16* __restrict__ Psw,
                             const __hip_bfloat16* __restrict__ PmuA,
                             const __hip_bfloat16* __restrict__ PmuB,
                             float* __restrict__ out) {
  __shared__ __attribute__((aligned(16))) char scratch[4 * PW_BYTES];  // 28 KB

  const int tid = threadIdx.x;
  const int wave = tid >> 6, lane = tid & 63;
  const int q = lane >> 4, l4 = lane & 15;
  const int base_pt = blockIdx.x * 128 + wave * 32;
  const float alpha = alpha_g[0];

  char* pw = scratch + wave * PW_BYTES;
  __hip_bfloat16* xsw = (__hip_bfloat16*)pw;           // [32][XROW] bf16 staging
  float* pmxw = (float*)pw;                            // [32][32] f32 (xsw dead)
  __hip_bfloat16* wtw = (__hip_bfloat16*)(pw + 4608);  // [32][WT_PITCH] bf16

  const bf16x8* PswF = (const bf16x8*)Psw;    // frag idx = k*512 + f*64 + lane
  const bf16x8* PmuAF = (const bf16x8*)PmuA;  // frag idx = f*64 + lane
  const bf16x8* PmuBF = (const bf16x8*)PmuB;

  // x master, C-layout: xm[mt][nt][r] = x[dim = mt*16+q*4+r][pt = nt*16+l4]
  f32x4 xm[4][2];
#pragma unroll
  for (int mt = 0; mt < 4; ++mt)
#pragma unroll
    for (int nt = 0; nt < 2; ++nt)
      xm[mt][nt] = *(const f32x4*)&x_in[(base_pt + nt * 16 + l4) * 64 + mt * 16 + q * 4];

  // e for pmx spill: cluster row mtc*16 + q*4 + r  ->  ev[mtc][r]
  f32x4 ev[2];
#pragma unroll
  for (int mtc = 0; mtc < 2; ++mtc) ev[mtc] = *(const f32x4*)&e_g[mtc * 16 + q * 4];

  const f32x4 Z4 = {0.f, 0.f, 0.f, 0.f};

  // pipeline state: static-named double buffers (rule #20: no runtime idx)
  bf16x8 apA[4][2], apB[4][2];
  f32x4 yA[4][2], yB[4][2];
  f32x4 accY[4][2];
  float lsum0, lsum1;
  bf16x8 bx[2][2];

  auto loadap = [&](bf16x8(&ap)[4][2], int k) {
#pragma unroll
    for (int mt = 0; mt < 4; ++mt)
#pragma unroll
      for (int s = 0; s < 2; ++s) ap[mt][s] = PswF[k * 512 + (mt * 2 + s) * 64 + lane];
  };
  // s-outer emission (R9): 8 independent s=0 MFMAs, then the 8 s=1 MFMAs
  auto mfma16 = [&](f32x4(&y)[4][2], const bf16x8(&ap)[4][2]) {
#pragma unroll
    for (int mt = 0; mt < 4; ++mt)
#pragma unroll
      for (int nt = 0; nt < 2; ++nt)
        y[mt][nt] = __builtin_amdgcn_mfma_f32_16x16x32_bf16(ap[mt][0], bx[0][nt], Z4, 0, 0, 0);
#pragma unroll
    for (int mt = 0; mt < 4; ++mt)
#pragma unroll
      for (int nt = 0; nt < 2; ++nt)
        y[mt][nt] = __builtin_amdgcn_mfma_f32_16x16x32_bf16(ap[mt][1], bx[1][nt], y[mt][nt], 0, 0, 0);
  };
  // softmax chain for one k on a previously-computed y
  auto chain = [&](const f32x4(&y)[4][2], int k) {
    f32x4 d0 = xm[0][0] * y[0][0];
    f32x4 d1 = xm[0][1] * y[0][1];
#pragma unroll
    for (int mt = 1; mt < 4; ++mt) {
      d0 += xm[mt][0] * y[mt][0];
      d1 += xm[mt][1] * y[mt][1];
    }
    float xy0 = (d0[0] + d0[1]) + (d0[2] + d0[3]);
    float xy1 = (d1[0] + d1[1]) + (d1[2] + d1[3]);
    xy0 = red32(red16(xy0));
    xy1 = red32(red16(xy1));
    const float pk0 = pmxw[k * 32 + l4];  // includes e_k
    const float pk1 = pmxw[k * 32 + 16 + l4];
    const float w0 = __expf(pk0 - 0.5f * xy0);
    const float w1 = __expf(pk1 - 0.5f * xy1);
    lsum0 += w0;
    lsum1 += w1;
    if (q == 0) {
      wtw[l4 * WT_PITCH + k] = __float2bfloat16(w0);
      wtw[(16 + l4) * WT_PITCH + k] = __float2bfloat16(w1);
    }
#pragma unroll
    for (int mt = 0; mt < 4; ++mt) {
      accY[mt][0] += w0 * y[mt][0];
      accY[mt][1] += w1 * y[mt][1];
    }
  };

#pragma unroll 1
  for (int it = 0; it < NITER; ++it) {
    // ---- issue k=0/k=1 fragment loads first (cover L2 latency w/ pmx) ----
    loadap(apA, 0);
    loadap(apB, 1);

    // ---- stage x (bf16) into wave-private rows [pt][dim], XROW-padded ----
#pragma unroll
    for (int mt = 0; mt < 4; ++mt)
#pragma unroll
      for (int nt = 0; nt < 2; ++nt) {
        uint2 v;
        v.x = pk_bf16(xm[mt][nt][0], xm[mt][nt][1]);
        v.y = pk_bf16(xm[mt][nt][2], xm[mt][nt][3]);
        *(uint2*)&xsw[(nt * 16 + l4) * XROW + mt * 16 + q * 4] = v;
      }

    // ---- B-frags of x: B[kk=dim=s*32+q*8+j][n=pt=l4] (constant over k) ----
#pragma unroll
    for (int s = 0; s < 2; ++s)
#pragma unroll
      for (int nt = 0; nt < 2; ++nt)
        bx[s][nt] = *(const bf16x8*)&xsw[(nt * 16 + l4) * XROW + s * 32 + q * 8];

    // ---- pmx GEMM (s-outer) ----
    f32x4 pmx[2][2];
#pragma unroll
    for (int mtc = 0; mtc < 2; ++mtc)
#pragma unroll
      for (int nt = 0; nt < 2; ++nt)
        pmx[mtc][nt] =
            __builtin_amdgcn_mfma_f32_16x16x32_bf16(PmuAF[(mtc * 2) * 64 + lane], bx[0][nt], Z4, 0, 0, 0);
#pragma unroll
    for (int mtc = 0; mtc < 2; ++mtc)
#pragma unroll
      for (int nt = 0; nt < 2; ++nt)
        pmx[mtc][nt] = __builtin_amdgcn_mfma_f32_16x16x32_bf16(PmuAF[(mtc * 2 + 1) * 64 + lane],
                                                               bx[1][nt], pmx[mtc][nt], 0, 0, 0);
    // spill pmx + e (folded) to wave-private LDS [cluster32][pt32] f32
#pragma unroll
    for (int mtc = 0; mtc < 2; ++mtc)
#pragma unroll
      for (int nt = 0; nt < 2; ++nt)
#pragma unroll
        for (int r = 0; r < 4; ++r)
          pmxw[(mtc * 16 + q * 4 + r) * 32 + nt * 16 + l4] = pmx[mtc][nt][r] + ev[mtc][r];

#pragma unroll
    for (int mt = 0; mt < 4; ++mt)
#pragma unroll
      for (int nt = 0; nt < 2; ++nt) accY[mt][nt] = Z4;
    lsum0 = 0.f;
    lsum1 = 0.f;

    // ---- 2-deep pipelined k-loop: MFMAs for k+1 issue before chain for k ---
    mfma16(yA, apA);  // y_0
    loadap(apA, 2);
#pragma unroll 1
    for (int kp = 0; kp < 15; ++kp) {
      const int k0 = 2 * kp;
      mfma16(yB, apB);               // y_{k0+1}
      loadap(apB, k0 + 3);           // consumed 1 pair later (~500 cyc)
      chain(yA, k0);                 // y_{k0} issued a full step ago
      mfma16(yA, apA);               // y_{k0+2}
      loadap(apA, (k0 + 4) & 31);    // kp=14 wraps to 0: dead load, harmless
      chain(yB, k0 + 1);
    }
    mfma16(yB, apB);  // y_31
    chain(yA, 30);
    chain(yB, 31);

    // ---- pacc[dim][pt] = sum_k Pmu[k][dim] * wt[k][pt]  (one K=32 GEMM) ----
    bf16x8 wtf[2];
#pragma unroll
    for (int nt = 0; nt < 2; ++nt)
      wtf[nt] = *(const bf16x8*)&wtw[(nt * 16 + l4) * WT_PITCH + q * 8];
    f32x4 pacc[4][2];
#pragma unroll
    for (int mt = 0; mt < 4; ++mt) {
      bf16x8 a = PmuBF[mt * 64 + lane];
      pacc[mt][0] = __builtin_amdgcn_mfma_f32_16x16x32_bf16(a, wtf[0], Z4, 0, 0, 0);
      pacc[mt][1] = __builtin_amdgcn_mfma_f32_16x16x32_bf16(a, wtf[1], Z4, 0, 0, 0);
    }

    // ---- x += (alpha/l) * (pacc - accY) ----
    const float c0 = alpha / lsum0;
    const float c1 = alpha / lsum1;
#pragma unroll
    for (int mt = 0; mt < 4; ++mt) {
      xm[mt][0] += c0 * (pacc[mt][0] - accY[mt][0]);
      xm[mt][1] += c1 * (pacc[mt][1] - accY[mt][1]);
    }
  }  // iterations

  // ---- direct f32x4 stores: 64B-contiguous per quad-row, fully in-bounds ---
#pragma unroll
  for (int mt = 0; mt < 4; ++mt)
#pragma unroll
    for (int nt = 0; nt < 2; ++nt)
      *(f32x4*)&out[(base_pt + nt * 16 + l4) * 64 + mt * 16 + q * 4] = xm[mt][nt];
}

extern "C" void kernel_launch(void* const* d_in, const int* in_sizes, int n_in,
                              void* d_out, int out_size, void* d_ws, size_t ws_size,
                              hipStream_t stream) {
  (void)in_sizes; (void)n_in; (void)out_size; (void)ws_size;
  const float* x = (const float*)d_in[0];
  const float* c = (const float*)d_in[1];
  const float* mu = (const float*)d_in[2];
  const float* A = (const float*)d_in[3];
  const float* alpha = (const float*)d_in[4];
  float* out = (float*)d_out;

  char* ws = (char*)d_ws;
  float* Pmu_g = (float*)(ws);                           // 8192 B
  float* e_g = (float*)(ws + 8192);                      // 128 B (pad to 256)
  __hip_bfloat16* PmuA = (__hip_bfloat16*)(ws + 8448);   // 4096 B
  __hip_bfloat16* PmuB = (__hip_bfloat16*)(ws + 12544);  // 4096 B
  __hip_bfloat16* Psw = (__hip_bfloat16*)(ws + 16640);   // 262144 B

  precompute1<<<32, 256, 0, stream>>>(A, mu, c, Pmu_g, e_g, Psw);
  precompute2<<<1, 256, 0, stream>>>(Pmu_g, PmuA, PmuB);
  denoise_main<<<512, 256, 0, stream>>>(x, e_g, alpha, Psw, PmuA, PmuB, out);
}

// Round 8
// 292.817 us; speedup vs baseline: 1.8816x; 1.8816x over previous
//
#include <hip/hip_runtime.h>
#include <hip/hip_bf16.h>

// DenoisingPotential: x_{t+1} = x_t + alpha * grad_phi(x_t), 10 iters.
// grad = (pacc - sum_k w_k y_k)/l,  y_k = P_k x,  w_k = exp(e_k + Pmu_k.x - 0.5 x.y_k)
//
// R11: counter-semantics fix (MfmaUtil/VALUBusy are CU-union of 4 SIMDs) shows
// R5-R9 SIMDs are ~73% idle: at the 128-VGPR allocator cap the 8 Psw loads/k
// can't all fly -> batch-serialized L2 latency ~1500 cyc/k-step. R6's LDS
// staging removed the result-regs but its __syncthreads drained vmcnt(0) per
// k-step (T4 anti-pattern). R11 = R6 staging + counted vmcnt + raw s_barrier:
// 4 bufs, prefetch distance 2, per step {stage(k+2); ds_read; MFMA s-outer;
// chain; vmcnt(2); s_barrier} -- staging latency never exposed, no drain.
// Steps 30/31 wrap-stage k=0/1 (pre-stages next iteration; uniform loop).
// R10's 2-deep reg pipeline reverted (spilled: FETCH 425 MB).

typedef __attribute__((ext_vector_type(4))) float f32x4;
typedef __attribute__((ext_vector_type(8))) short bf16x8;  // 8 bf16 = 4 VGPRs

#define KC 32
#define NITER 10
#define XROW 72        // bf16 elems per point-row in xs staging (pad vs 64)
#define WT_PITCH 40    // bf16 pitch of weight stash (pad vs 32)
#define PW_BYTES 7168  // per-wave: xsw(4608, aliased by pmxw 4096) + wtw(2560)
#define PSTG 8192      // one k's P fragments (64x64 bf16)
#define NBUF 4         // staging buffers; 32 % 4 == 0 -> clean wrap across iters
// LDS total: 4*7168 + 4*8192 = 61440 B -> 2 blocks/CU

static __device__ __forceinline__ unsigned pk_bf16(float a, float b) {
  __hip_bfloat16 ha = __float2bfloat16(a), hb = __float2bfloat16(b);
  unsigned short ua = *(unsigned short*)&ha, ub = *(unsigned short*)&hb;
  return (unsigned)ua | ((unsigned)ub << 16);
}

// butterfly sum with lane^16: permlane16_swap is pure VALU (sum of the two
// outputs = x[l] + x[l^16] in every lane)
static __device__ __forceinline__ float red16(float x) {
#if __has_builtin(__builtin_amdgcn_permlane16_swap)
  int xi = __float_as_int(x);
  auto pr = __builtin_amdgcn_permlane16_swap(xi, xi, false, false);
  return __int_as_float(pr[0]) + __int_as_float(pr[1]);
#else
  int v = __builtin_amdgcn_ds_swizzle(__float_as_int(x), 0x401F);
  return x + __int_as_float(v);
#endif
}
// butterfly sum with lane^32 (VALU permlane32_swap)
static __device__ __forceinline__ float red32(float x) {
  int xi = __float_as_int(x);
  auto pr = __builtin_amdgcn_permlane32_swap(xi, xi, false, false);
  return __int_as_float(pr[0]) + __int_as_float(pr[1]);
}

// async global->LDS, 16B per lane; ldst is wave-uniform base (HW adds lane*16),
// gsrc is the per-lane source address.
static __device__ __forceinline__ void stage16(const void* gsrc, void* ldst) {
  __builtin_amdgcn_global_load_lds(
      (const __attribute__((address_space(1))) unsigned int*)gsrc,
      (__attribute__((address_space(3))) unsigned int*)ldst, 16, 0, 0);
}

// ---------------- precompute 1: per-k P = A^T A, Pmu, e, swizzled P ----------
__global__ void precompute1(const float* __restrict__ A, const float* __restrict__ mu,
                            const float* __restrict__ c,
                            float* __restrict__ Pmu_g, float* __restrict__ e_g,
                            __hip_bfloat16* __restrict__ Psw) {
  __shared__ float As[64 * 64];
  __shared__ float Pk[64 * 64];
  const int k = blockIdx.x, tid = threadIdx.x;
  const float* Ak = A + k * 4096;
  for (int idx = tid; idx < 1024; idx += 256)
    *(f32x4*)&As[idx * 4] = *(const f32x4*)&Ak[idx * 4];
  __syncthreads();

  // thread -> row i = tid>>2, col strip lg*16..lg*16+15
  const int i = tid >> 2, lg = tid & 3;
  float acc[16] = {};
  for (int j = 0; j < 64; ++j) {
    float ai = As[j * 64 + i];  // broadcast within quad
    const f32x4* row = (const f32x4*)&As[j * 64 + lg * 16];  // broadcast across i
#pragma unroll
    for (int g = 0; g < 4; ++g) {
      f32x4 v = row[g];
#pragma unroll
      for (int r = 0; r < 4; ++r) acc[g * 4 + r] += ai * v[r];
    }
  }
#pragma unroll
  for (int g = 0; g < 4; ++g)
#pragma unroll
    for (int r = 0; r < 4; ++r) Pk[i * 64 + lg * 16 + g * 4 + r] = acc[g * 4 + r];
  __syncthreads();

  if (tid < 64) {
    // Pmu[i] = sum_l P[l][i]*mu[l]  (P symmetric; transposed read = stride-1)
    float s = 0.f;
    for (int l = 0; l < 64; ++l) s += Pk[l * 64 + tid] * mu[k * 64 + l];
    Pmu_g[k * 64 + tid] = s;
    float v = mu[k * 64 + tid] * s;
#pragma unroll
    for (int off = 1; off < 64; off <<= 1) v += __shfl_xor(v, off, 64);
    if (tid == 0) e_g[k] = c[k] - 0.5f * v;
  }

  // A-frag order for the main GEMM: flat idx = f*512 + lane*8 + j,
  // f=(mt,s): val = P[dim_in = s*32 + qq*8 + j][dim_out = mt*16 + l4]
  unsigned* Psw32 = (unsigned*)(Psw + k * 4096);
  for (int idx2 = tid; idx2 < 2048; idx2 += 256) {
    int idx = idx2 << 1;  // even j
    int f = idx >> 9, ln = (idx >> 3) & 63, j = idx & 7;
    int mt = f >> 1, s = f & 1, qq = ln >> 4, l4 = ln & 15;
    int col = mt * 16 + l4, rb = s * 32 + qq * 8 + j;
    Psw32[idx2] = pk_bf16(Pk[rb * 64 + col], Pk[(rb + 1) * 64 + col]);
  }
}

// ---------------- precompute 2: Pmu fragment swizzles -----------------------
__global__ void precompute2(const float* __restrict__ Pmu_g,
                            __hip_bfloat16* __restrict__ PmuA,
                            __hip_bfloat16* __restrict__ PmuB) {
  const int tid = threadIdx.x;
  // PmuA (pmx GEMM A-operand): A[m=cluster][kk=dim]; frag f=(mtc,s)
  for (int idx = tid; idx < 2048; idx += 256) {
    int f = idx >> 9, lane = (idx >> 3) & 63, j = idx & 7;
    int mtc = f >> 1, s = f & 1, qq = lane >> 4, l4 = lane & 15;
    PmuA[idx] = __float2bfloat16(Pmu_g[(mtc * 16 + l4) * 64 + s * 32 + qq * 8 + j]);
  }
  // PmuB (pacc GEMM A-operand): A[m=dim][kk=cluster]; frag f=mtd (K=32, 1 step)
  for (int idx = tid; idx < 2048; idx += 256) {
    int f = idx >> 9, lane = (idx >> 3) & 63, j = idx & 7;
    int qq = lane >> 4, l4 = lane & 15;
    PmuB[idx] = __float2bfloat16(Pmu_g[(qq * 8 + j) * 64 + f * 16 + l4]);
  }
}

// ---------------- main kernel ----------------------------------------------
// 256 thr (4 waves), 32 pts/wave, grid 512 (2 blocks/CU). P staged per k into
// 4 LDS buffers (block-cooperative, wave w stages frags 2w,2w+1), prefetch
// distance 2; per k-step: counted vmcnt(2) + raw s_barrier (never drain).
__launch_bounds__(256, 2)
__global__ void denoise_main(const float* __restrict__ x_in,
                             const float* __restrict__ e_g,
                             const float* __restrict__ alpha_g,
                             const __hip_bfloat16* __restrict__ Psw,
                             const __hip_bfloat16* __restrict__ PmuA,
                             const __hip_bfloat16* __restrict__ PmuB,
                             float* __restrict__ out) {
  __shared__ __attribute__((aligned(16))) char scratch[4 * PW_BYTES + NBUF * PSTG];  // 60 KB

  const int tid = threadIdx.x;
  const int wave = tid >> 6, lane = tid & 63;
  const int q = lane >> 4, l4 = lane & 15;
  const int base_pt = blockIdx.x * 128 + wave * 32;
  const float alpha = alpha_g[0];

  char* pw = scratch + wave * PW_BYTES;
  __hip_bfloat16* xsw = (__hip_bfloat16*)pw;           // [32][XROW] bf16 staging
  float* pmxw = (float*)pw;                            // [32][32] f32 (xsw dead)
  __hip_bfloat16* wtw = (__hip_bfloat16*)(pw + 4608);  // [32][WT_PITCH] bf16
  char* pstg = scratch + 4 * PW_BYTES;                 // [NBUF][PSTG] stage bufs

  const char* PswB = (const char*)Psw;        // k block = 8192 B, frag f = 1024 B
  const bf16x8* PmuAF = (const bf16x8*)PmuA;  // frag idx = f*64 + lane
  const bf16x8* PmuBF = (const bf16x8*)PmuB;

  // x master, C-layout: xm[mt][nt][r] = x[dim = mt*16+q*4+r][pt = nt*16+l4]
  f32x4 xm[4][2];
#pragma unroll
  for (int mt = 0; mt < 4; ++mt)
#pragma unroll
    for (int nt = 0; nt < 2; ++nt)
      xm[mt][nt] = *(const f32x4*)&x_in[(base_pt + nt * 16 + l4) * 64 + mt * 16 + q * 4];

  // e for pmx spill: cluster row mtc*16 + q*4 + r  ->  ev[mtc][r]
  f32x4 ev[2];
#pragma unroll
  for (int mtc = 0; mtc < 2; ++mtc) ev[mtc] = *(const f32x4*)&e_g[mtc * 16 + q * 4];

  const f32x4 Z4 = {0.f, 0.f, 0.f, 0.f};
  const int f0 = 2 * wave, f1 = 2 * wave + 1;  // this wave's staging fragments

  // ---- first-iteration staging prologue: k=0 -> buf0, k=1 -> buf1 ----
  stage16(PswB + f0 * 1024 + lane * 16, pstg + f0 * 1024);
  stage16(PswB + f1 * 1024 + lane * 16, pstg + f1 * 1024);
  stage16(PswB + PSTG + f0 * 1024 + lane * 16, pstg + PSTG + f0 * 1024);
  stage16(PswB + PSTG + f1 * 1024 + lane * 16, pstg + PSTG + f1 * 1024);

#pragma unroll 1
  for (int it = 0; it < NITER; ++it) {
    // ---- stage x (bf16) into wave-private rows [pt][dim], XROW-padded ----
#pragma unroll
    for (int mt = 0; mt < 4; ++mt)
#pragma unroll
      for (int nt = 0; nt < 2; ++nt) {
        uint2 v;
        v.x = pk_bf16(xm[mt][nt][0], xm[mt][nt][1]);
        v.y = pk_bf16(xm[mt][nt][2], xm[mt][nt][3]);
        *(uint2*)&xsw[(nt * 16 + l4) * XROW + mt * 16 + q * 4] = v;
      }

    // ---- B-frags of x: B[kk=dim=s*32+q*8+j][n=pt=l4] (constant over k) ----
    bf16x8 bx[2][2];
#pragma unroll
    for (int s = 0; s < 2; ++s)
#pragma unroll
      for (int nt = 0; nt < 2; ++nt)
        bx[s][nt] = *(const bf16x8*)&xsw[(nt * 16 + l4) * XROW + s * 32 + q * 8];

    // ---- pmx GEMM (s-outer) ----
    f32x4 pmx[2][2];
#pragma unroll
    for (int mtc = 0; mtc < 2; ++mtc)
#pragma unroll
      for (int nt = 0; nt < 2; ++nt)
        pmx[mtc][nt] =
            __builtin_amdgcn_mfma_f32_16x16x32_bf16(PmuAF[(mtc * 2) * 64 + lane], bx[0][nt], Z4, 0, 0, 0);
#pragma unroll
    for (int mtc = 0; mtc < 2; ++mtc)
#pragma unroll
      for (int nt = 0; nt < 2; ++nt)
        pmx[mtc][nt] = __builtin_amdgcn_mfma_f32_16x16x32_bf16(PmuAF[(mtc * 2 + 1) * 64 + lane],
                                                               bx[1][nt], pmx[mtc][nt], 0, 0, 0);
    // spill pmx + e (folded) to wave-private LDS [cluster32][pt32] f32
#pragma unroll
    for (int mtc = 0; mtc < 2; ++mtc)
#pragma unroll
      for (int nt = 0; nt < 2; ++nt)
#pragma unroll
        for (int r = 0; r < 4; ++r)
          pmxw[(mtc * 16 + q * 4 + r) * 32 + nt * 16 + l4] = pmx[mtc][nt][r] + ev[mtc][r];

    f32x4 accY[4][2];
#pragma unroll
    for (int mt = 0; mt < 4; ++mt)
#pragma unroll
      for (int nt = 0; nt < 2; ++nt) accY[mt][nt] = Z4;
    float lsum0 = 0.f, lsum1 = 0.f;

    // prologue sync: wait own k=0 staging (vmcnt(2): k=1's 2 loads may fly),
    // then barrier so every wave's buf0 contribution is visible
    asm volatile("s_waitcnt vmcnt(2)" ::: "memory");
    __builtin_amdgcn_s_barrier();
    asm volatile("" ::: "memory");

    // ---- k-loop: counted-vmcnt pipeline, one raw barrier per k, no drain ---
#pragma unroll 2
    for (int k = 0; k < KC; ++k) {
      // stage k+2 (wraps: steps 30/31 pre-stage next iteration's k=0/1)
      {
        const int ks = (k + 2) & (KC - 1);
        const char* ps = PswB + ks * PSTG;
        char* pd = pstg + (ks & (NBUF - 1)) * PSTG;
        stage16(ps + f0 * 1024 + lane * 16, pd + f0 * 1024);
        stage16(ps + f1 * 1024 + lane * 16, pd + f1 * 1024);
      }

      // fragments for k from staged LDS (compiler-tracked lgkmcnt)
      const char* pc = pstg + (k & (NBUF - 1)) * PSTG;
      bf16x8 ap[4][2];
#pragma unroll
      for (int mt = 0; mt < 4; ++mt)
#pragma unroll
        for (int s = 0; s < 2; ++s)
          ap[mt][s] = *(const bf16x8*)(pc + (mt * 2 + s) * 1024 + lane * 16);

      // y = P x, s-outer emission (R9): 8 independent MFMAs, then 8 dependents
      f32x4 y[4][2];
#pragma unroll
      for (int mt = 0; mt < 4; ++mt)
#pragma unroll
        for (int nt = 0; nt < 2; ++nt)
          y[mt][nt] = __builtin_amdgcn_mfma_f32_16x16x32_bf16(ap[mt][0], bx[0][nt], Z4, 0, 0, 0);
#pragma unroll
      for (int mt = 0; mt < 4; ++mt)
#pragma unroll
        for (int nt = 0; nt < 2; ++nt)
          y[mt][nt] =
              __builtin_amdgcn_mfma_f32_16x16x32_bf16(ap[mt][1], bx[1][nt], y[mt][nt], 0, 0, 0);

      // xy[pt] = x . y : packed fp32 FMAs, chain depth 4
      f32x4 d0 = xm[0][0] * y[0][0];
      f32x4 d1 = xm[0][1] * y[0][1];
#pragma unroll
      for (int mt = 1; mt < 4; ++mt) {
        d0 += xm[mt][0] * y[mt][0];
        d1 += xm[mt][1] * y[mt][1];
      }
      float xy0 = (d0[0] + d0[1]) + (d0[2] + d0[3]);
      float xy1 = (d1[0] + d1[1]) + (d1[2] + d1[3]);
      xy0 = red32(red16(xy0));
      xy1 = red32(red16(xy1));

      const float pk0 = pmxw[k * 32 + l4];  // includes e_k
      const float pk1 = pmxw[k * 32 + 16 + l4];
      const float w0 = __expf(pk0 - 0.5f * xy0);
      const float w1 = __expf(pk1 - 0.5f * xy1);
      lsum0 += w0;
      lsum1 += w1;
      if (q == 0) {
        wtw[l4 * WT_PITCH + k] = __float2bfloat16(w0);
        wtw[(16 + l4) * WT_PITCH + k] = __float2bfloat16(w1);
      }
      // accY += w * y (packed fp32 FMA)
#pragma unroll
      for (int mt = 0; mt < 4; ++mt) {
        accY[mt][0] += w0 * y[mt][0];
        accY[mt][1] += w1 * y[mt][1];
      }

      // counted sync: own stage(k+1) done (stage(k+2)'s 2 loads may fly);
      // barrier makes all waves' buf[k+1] contributions visible. NO drain.
      asm volatile("s_waitcnt vmcnt(2)" ::: "memory");
      __builtin_amdgcn_s_barrier();
      asm volatile("" ::: "memory");
    }

    // ---- pacc[dim][pt] = sum_k Pmu[k][dim] * wt[k][pt]  (one K=32 GEMM) ----
    bf16x8 wtf[2];
#pragma unroll
    for (int nt = 0; nt < 2; ++nt)
      wtf[nt] = *(const bf16x8*)&wtw[(nt * 16 + l4) * WT_PITCH + q * 8];
    f32x4 pacc[4][2];
#pragma unroll
    for (int mt = 0; mt < 4; ++mt) {
      bf16x8 a = PmuBF[mt * 64 + lane];
      pacc[mt][0] = __builtin_amdgcn_mfma_f32_16x16x32_bf16(a, wtf[0], Z4, 0, 0, 0);
      pacc[mt][1] = __builtin_amdgcn_mfma_f32_16x16x32_bf16(a, wtf[1], Z4, 0, 0, 0);
    }

    // ---- x += (alpha/l) * (pacc - accY) ----
    const float c0 = alpha / lsum0;
    const float c1 = alpha / lsum1;
#pragma unroll
    for (int mt = 0; mt < 4; ++mt) {
      xm[mt][0] += c0 * (pacc[mt][0] - accY[mt][0]);
      xm[mt][1] += c1 * (pacc[mt][1] - accY[mt][1]);
    }
  }  // iterations

  // ---- direct f32x4 stores: 64B-contiguous per quad-row, fully in-bounds ---
#pragma unroll
  for (int mt = 0; mt < 4; ++mt)
#pragma unroll
    for (int nt = 0; nt < 2; ++nt)
      *(f32x4*)&out[(base_pt + nt * 16 + l4) * 64 + mt * 16 + q * 4] = xm[mt][nt];
}

extern "C" void kernel_launch(void* const* d_in, const int* in_sizes, int n_in,
                              void* d_out, int out_size, void* d_ws, size_t ws_size,
                              hipStream_t stream) {
  (void)in_sizes; (void)n_in; (void)out_size; (void)ws_size;
  const float* x = (const float*)d_in[0];
  const float* c = (const float*)d_in[1];
  const float* mu = (const float*)d_in[2];
  const float* A = (const float*)d_in[3];
  const float* alpha = (const float*)d_in[4];
  float* out = (float*)d_out;

  char* ws = (char*)d_ws;
  float* Pmu_g = (float*)(ws);                           // 8192 B
  float* e_g = (float*)(ws + 8192);                      // 128 B (pad to 256)
  __hip_bfloat16* PmuA = (__hip_bfloat16*)(ws + 8448);   // 4096 B
  __hip_bfloat16* PmuB = (__hip_bfloat16*)(ws + 12544);  // 4096 B
  __hip_bfloat16* Psw = (__hip_bfloat16*)(ws + 16640);   // 262144 B

  precompute1<<<32, 256, 0, stream>>>(A, mu, c, Pmu_g, e_g, Psw);
  precompute2<<<1, 256, 0, stream>>>(Pmu_g, PmuA, PmuB);
  denoise_main<<<512, 256, 0, stream>>>(x, e_g, alpha, Psw, PmuA, PmuB, out);
}